// Round 3
// baseline (1174.834 us; speedup 1.0000x reference)
//
#include <hip/hip_runtime.h>
#include <hip/hip_bf16.h>
#include <math.h>

typedef __bf16 bf16_t;
typedef __bf16 bf16x8 __attribute__((ext_vector_type(8)));
typedef float  f32x4  __attribute__((ext_vector_type(4)));

#define MFMA16(a,b,c) __builtin_amdgcn_mfma_f32_16x16x32_bf16((a),(b),(c),0,0,0)

namespace {
constexpr int D   = 64;
constexpr int DIN = 192;
constexpr int NN  = 30000;
constexpr int NE  = 480000;
constexpr int NCH = NE / 32;     // 15000 wave-chunks of 32 edges
constexpr int GRID = 1250;       // 5000 waves -> exactly 3 chunks each
constexpr int SH  = 72;          // hidden LDS stride (16B-aligned rows, read-conflict-free)
constexpr int SLOT = 32 * SH;    // 2304 elems per hidden slot

constexpr int W0_SZ = 64 * 192;  // 12288 elems, W^T row-major [n][k]
constexpr int W1_SZ = 64 * 64;   // 4096

constexpr size_t WS_AGG   = 0;                                 // fp32 agg [NN*D]
constexpr size_t AGG_B    = (size_t)NN * D * 4;
constexpr size_t WS_WT    = AGG_B;                             // bf16 weights
constexpr size_t WT_B     = (size_t)(4 * W0_SZ + 4 * W1_SZ) * 2;
constexpr size_t WS_NF    = WS_WT + WT_B;                      // bf16 node_feat
constexpr size_t NF_B     = (size_t)NN * D * 2;
constexpr size_t WS_FLAG  = WS_NF + NF_B;
}

// ---- dtype-generic 8-elem bf16 fragment loads (16B / 32B aligned callsites)
__device__ __forceinline__ bf16x8 ldA(const bf16_t* p) { return *(const bf16x8*)p; }
__device__ __forceinline__ bf16x8 ldA(const float* p) {
  const float4* q4 = (const float4*)p;
  const float4 u = q4[0], v = q4[1];
  bf16x8 r;
  r[0] = (bf16_t)u.x; r[1] = (bf16_t)u.y; r[2] = (bf16_t)u.z; r[3] = (bf16_t)u.w;
  r[4] = (bf16_t)v.x; r[5] = (bf16_t)v.y; r[6] = (bf16_t)v.z; r[7] = (bf16_t)v.w;
  return r;
}

__device__ __forceinline__ float silu_f(float v) { return v / (1.f + __expf(-v)); }
__device__ __forceinline__ float sigm_f(float v) { return 1.f / (1.f + __expf(-v)); }

// layer0 both branches in one pass (shared A-frags):
// [32 edges x 192] @ [192 x 64] twice. A: nf_bf gathers + mid (ef global or
// LDS e_new). B: straight from global (L2-resident W^T).
template<typename TM>
__device__ __forceinline__ void mlp_l0_pair(f32x4 acc[2][4], f32x4 acg[2][4],
    const bf16_t* __restrict__ wL, const bf16_t* __restrict__ wG,
    const bf16_t* __restrict__ nfb, const TM* __restrict__ mid,
    int sA, int sB, int dA, int dB, int midA, int midB, int midStride,
    int m, int q)
{
  const f32x4 z = {0.f, 0.f, 0.f, 0.f};
  #pragma unroll
  for (int mt = 0; mt < 2; ++mt)
    #pragma unroll
    for (int nt = 0; nt < 4; ++nt) { acc[mt][nt] = z; acg[mt][nt] = z; }
  #pragma unroll
  for (int kt = 0; kt < 6; ++kt) {
    const int ko = (kt & 1) * 32 + q * 8;
    bf16x8 a0, a1;
    if (kt < 2)      { a0 = ldA(nfb + sA * D + ko);           a1 = ldA(nfb + sB * D + ko); }
    else if (kt < 4) { a0 = ldA(mid + midA * midStride + ko); a1 = ldA(mid + midB * midStride + ko); }
    else             { a0 = ldA(nfb + dA * D + ko);           a1 = ldA(nfb + dB * D + ko); }
    const bf16_t* bl = wL + m * 192 + kt * 32 + q * 8;
    const bf16_t* bg = wG + m * 192 + kt * 32 + q * 8;
    #pragma unroll
    for (int nt = 0; nt < 4; ++nt) {
      const bf16x8 bL8 = ldA(bl + nt * 16 * 192);
      acc[0][nt] = MFMA16(a0, bL8, acc[0][nt]);
      acc[1][nt] = MFMA16(a1, bL8, acc[1][nt]);
      const bf16x8 bG8 = ldA(bg + nt * 16 * 192);
      acg[0][nt] = MFMA16(a0, bG8, acg[0][nt]);
      acg[1][nt] = MFMA16(a1, bG8, acg[1][nt]);
    }
  }
}

// layer1: [32 x 64] @ [64 x 64]. A from wave-private LDS hidden, B from global.
__device__ __forceinline__ void mlp_l1(f32x4 acc[2][4], const bf16_t* __restrict__ h,
                                       const bf16_t* __restrict__ w1t, int m, int q)
{
  const f32x4 z = {0.f, 0.f, 0.f, 0.f};
  #pragma unroll
  for (int mt = 0; mt < 2; ++mt)
    #pragma unroll
    for (int nt = 0; nt < 4; ++nt) acc[mt][nt] = z;
  #pragma unroll
  for (int kt = 0; kt < 2; ++kt) {
    const int ko = kt * 32 + q * 8;
    const bf16x8 a0 = ldA(h + m * SH + ko);
    const bf16x8 a1 = ldA(h + (m + 16) * SH + ko);
    const bf16_t* wb = w1t + m * 64 + ko;
    #pragma unroll
    for (int nt = 0; nt < 4; ++nt) {
      const bf16x8 b = ldA(wb + nt * 16 * 64);
      acc[0][nt] = MFMA16(a0, b, acc[0][nt]);
      acc[1][nt] = MFMA16(a1, b, acc[1][nt]);
    }
  }
}

// C-layout acc (+bias, silu) -> wave-private LDS hidden [row][n] bf16
template<typename TB>
__device__ __forceinline__ void hidden_silu(const f32x4 acc[2][4],
    const TB* __restrict__ bias, bf16_t* __restrict__ h, int m, int q)
{
  #pragma unroll
  for (int nt = 0; nt < 4; ++nt) {
    const float bv = (float)bias[nt * 16 + m];
    #pragma unroll
    for (int mt = 0; mt < 2; ++mt)
      #pragma unroll
      for (int r = 0; r < 4; ++r)
        h[(mt * 16 + q * 4 + r) * SH + nt * 16 + m] =
            (bf16_t)silu_f(acc[mt][nt][r] + bv);
  }
}

// ---- dtype detection (HW-verified in R2): even-index uint16s of fp32 data
// have uniform exponent fields; bf16 data has sane exponents.
__global__ void detect_kernel(const void* w0, int* flag) {
  __shared__ int cnt;
  if (threadIdx.x == 0) cnt = 0;
  __syncthreads();
  const unsigned short* u = (const unsigned short*)w0;
  const unsigned short v = u[2 * threadIdx.x];
  const int e = (v >> 7) & 0xFF;
  atomicAdd(&cnt, (e >= 100 && e <= 140) ? 1 : 0);
  __syncthreads();
  if (threadIdx.x == 0) *flag = (cnt >= 128) ? 1 : 0;  // 1 = bf16, 0 = fp32
}

struct PrepArgs { const void* w[8]; bf16_t* o[8]; };

// weights -> bf16 W^T[n][k] row-major in ws (strides 192 / 64)
template<typename T>
__global__ void prep_w_kernel(const int* flag, int want, PrepArgs a) {
  if (*flag != want) return;
  const int b = blockIdx.x, t = threadIdx.x;
  const T* w = (const T*)a.w[b];
  bf16_t* o = a.o[b];
  if (b < 4) {
    for (int i = t; i < DIN * D; i += 256) o[(i & 63) * 192 + (i >> 6)] = (bf16_t)(float)w[i];
  } else {
    for (int i = t; i < D * D; i += 256)  o[(i & 63) * 64  + (i >> 6)] = (bf16_t)(float)w[i];
  }
}

// node_feat -> bf16 copy in ws
template<typename T>
__global__ void prep_nf_kernel(const int* flag, int want,
                               const T* __restrict__ nf, bf16_t* __restrict__ nfb) {
  if (*flag != want) return;
  const int n8 = NN * D / 8;
  for (int i = blockIdx.x * 256 + threadIdx.x; i < n8; i += gridDim.x * 256)
    *(bf16x8*)(nfb + i * 8) = ldA(nf + i * 8);
}

template<typename T>
__global__ __launch_bounds__(256, 4) void fused_kernel(
    const int* __restrict__ flag, int want,
    const bf16_t* __restrict__ nfb, const T* __restrict__ ef,
    const int* __restrict__ src, const int* __restrict__ dst,
    const T* __restrict__ eLb0, const T* __restrict__ eLb1,
    const T* __restrict__ eGb0, const T* __restrict__ eGb1,
    const T* __restrict__ nLb0, const T* __restrict__ nLb1,
    const T* __restrict__ nGb0, const T* __restrict__ nGb1,
    const bf16_t* __restrict__ wt, float* __restrict__ agg,
    T* __restrict__ out_e)
{
  if (*flag != want) return;
  __shared__ __align__(16) bf16_t sm[4 * 2 * SLOT];   // 36,864 B -> 4 blocks/CU
  const int t = threadIdx.x;
  const int lane = t & 63;
  const int w = t >> 6;
  const int m = lane & 15;
  const int q = lane >> 4;

  bf16_t* hB = sm + w * (2 * SLOT);   // wave-private slots: no barriers anywhere
  bf16_t* hC = hB + SLOT;

  const bf16_t* w0eL = wt;
  const bf16_t* w0eG = wt + W0_SZ;
  const bf16_t* w0nL = wt + 2 * W0_SZ;
  const bf16_t* w0nG = wt + 3 * W0_SZ;
  const bf16_t* w1eL = wt + 4 * W0_SZ;
  const bf16_t* w1eG = wt + 4 * W0_SZ + W1_SZ;
  const bf16_t* w1nL = wt + 4 * W0_SZ + 2 * W1_SZ;
  const bf16_t* w1nG = wt + 4 * W0_SZ + 3 * W1_SZ;

  const int wid = blockIdx.x * 4 + w;
  for (int c = wid; c < NCH; c += GRID * 4) {
    const int e0 = c * 32;
    const int eA = e0 + m, eB = eA + 16;
    const int sA = src[eA], sB = src[eB];
    const int dA = dst[eA], dB = dst[eB];

    f32x4 acc[2][4], acg[2][4];

    // ===== edge MLP =====
    mlp_l0_pair(acc, acg, w0eL, w0eG, nfb, ef, sA, sB, dA, dB, eA, eB, D, m, q);
    hidden_silu(acc, eLb0, hB, m, q);
    hidden_silu(acg, eGb0, hC, m, q);
    mlp_l1(acc, hB, w1eL, m, q);
    mlp_l1(acg, hC, w1eG, m, q);

    // epilogue: e_new = ef + silu(h1)*sigmoid(g1); write out + stash in hB
    #pragma unroll
    for (int nt = 0; nt < 4; ++nt) {
      const int n = nt * 16 + m;
      const float bL = (float)eLb1[n];
      const float bG = (float)eGb1[n];
      #pragma unroll
      for (int mt = 0; mt < 2; ++mt)
        #pragma unroll
        for (int r = 0; r < 4; ++r) {
          const int e = e0 + mt * 16 + q * 4 + r;
          const float hv = silu_f(acc[mt][nt][r] + bL);
          const float gv = sigm_f(acg[mt][nt][r] + bG);
          const float val = (float)ef[e * D + n] + hv * gv;
          out_e[e * D + n] = (T)val;
          hB[(mt * 16 + q * 4 + r) * SH + n] = (bf16_t)val;  // e_new (wave-local)
        }
    }

    // ===== node MLP (mid operand = e_new in hB) =====
    mlp_l0_pair(acc, acg, w0nL, w0nG, nfb, hB, sA, sB, dA, dB, m, m + 16, SH, m, q);
    hidden_silu(acc, nLb0, hC, m, q);   // hC dead after l1(acg,...) above
    hidden_silu(acg, nGb0, hB, m, q);   // hB dead after l0_pair reads
    mlp_l1(acc, hC, w1nL, m, q);
    mlp_l1(acg, hB, w1nG, m, q);

    int d8[2][4];
    #pragma unroll
    for (int mt = 0; mt < 2; ++mt)
      #pragma unroll
      for (int r = 0; r < 4; ++r)
        d8[mt][r] = dst[e0 + mt * 16 + q * 4 + r];

    #pragma unroll
    for (int nt = 0; nt < 4; ++nt) {
      const int n = nt * 16 + m;
      const float bL = (float)nLb1[n];
      const float bG = (float)nGb1[n];
      #pragma unroll
      for (int mt = 0; mt < 2; ++mt)
        #pragma unroll
        for (int r = 0; r < 4; ++r) {
          const float hv = silu_f(acc[mt][nt][r] + bL);
          const float gv = sigm_f(acg[mt][nt][r] + bG);
          atomicAdd(&agg[d8[mt][r] * D + n], hv * gv);
        }
    }
  }
}

// h_new = node_feat + agg @ node_out_W   (one wave per node)
template<typename T>
__global__ __launch_bounds__(256) void node_out_kernel(
    const int* __restrict__ flag, int want,
    const T* __restrict__ nf, const float* __restrict__ agg,
    const T* __restrict__ Wo, T* __restrict__ out_h)
{
  if (*flag != want) return;
  __shared__ float wsh[D * D];
  const int t = threadIdx.x;
  for (int i = t; i < D * D; i += 256) wsh[i] = (float)Wo[i];
  __syncthreads();
  const int node = blockIdx.x * 4 + (t >> 6);
  const int j = t & 63;
  const float* arow = agg + node * D;
  float acc = 0.f;
  #pragma unroll
  for (int k = 0; k < D; ++k) acc = fmaf(arow[k], wsh[k * D + j], acc);
  out_h[node * D + j] = (T)((float)nf[node * D + j] + acc);
}

template<typename T>
static void launch_all(void* const* d_in, void* d_out,
                       const int* flag, int want, const bf16_t* wt,
                       const bf16_t* nfb, float* agg, hipStream_t stream) {
  const T* nf  = (const T*)d_in[0];
  const T* ef  = (const T*)d_in[1];
  const int* src = (const int*)d_in[2];
  const int* dst = (const int*)d_in[3];
  T* out_h = (T*)d_out;
  T* out_e = out_h + (size_t)NN * D;

  prep_nf_kernel<T><<<512, 256, 0, stream>>>(flag, want, nf, (bf16_t*)nfb);
  fused_kernel<T><<<GRID, 256, 0, stream>>>(flag, want, nfb, ef, src, dst,
      (const T*)d_in[5],  (const T*)d_in[7],
      (const T*)d_in[9],  (const T*)d_in[11],
      (const T*)d_in[13], (const T*)d_in[15],
      (const T*)d_in[17], (const T*)d_in[19],
      wt, agg, out_e);
  node_out_kernel<T><<<NN / 4, 256, 0, stream>>>(flag, want, nf, agg,
      (const T*)d_in[20], out_h);
}

extern "C" void kernel_launch(void* const* d_in, const int* in_sizes, int n_in,
                              void* d_out, int out_size, void* d_ws, size_t ws_size,
                              hipStream_t stream) {
  float*  agg  = (float*)d_ws;
  bf16_t* wt   = (bf16_t*)((char*)d_ws + WS_WT);
  bf16_t* nfb  = (bf16_t*)((char*)d_ws + WS_NF);
  int*    flag = (int*)((char*)d_ws + WS_FLAG);

  hipMemsetAsync(d_ws, 0, AGG_B, stream);              // zero agg

  detect_kernel<<<1, 256, 0, stream>>>(d_in[4], flag); // probe eLW0 dtype

  PrepArgs pa;
  pa.w[0] = d_in[4];  pa.w[1] = d_in[8];  pa.w[2] = d_in[12]; pa.w[3] = d_in[16];
  pa.w[4] = d_in[6];  pa.w[5] = d_in[10]; pa.w[6] = d_in[14]; pa.w[7] = d_in[18];
  for (int i = 0; i < 4; ++i) pa.o[i]     = wt + i * W0_SZ;
  for (int j = 0; j < 4; ++j) pa.o[4 + j] = wt + 4 * W0_SZ + j * W1_SZ;
  prep_w_kernel<float> <<<8, 256, 0, stream>>>(flag, 0, pa);
  prep_w_kernel<bf16_t><<<8, 256, 0, stream>>>(flag, 1, pa);

  launch_all<float> (d_in, d_out, flag, 0, wt, nfb, agg, stream);
  launch_all<bf16_t>(d_in, d_out, flag, 1, wt, nfb, agg, stream);
}